// Round 8
// baseline (252.560 us; speedup 1.0000x reference)
//
#include <hip/hip_runtime.h>
#include <math.h>

#define NB 8
#define NA 256
#define NBD 256
#define NC 64
#define NF 129

struct alignas(8) cpx { float re, im; };

__device__ __forceinline__ cpx cmul(cpx a, cpx b){
  cpx r;
  r.re = fmaf(a.re, b.re, -(a.im * b.im));
  r.im = fmaf(a.re, b.im,  a.im * b.re);
  return r;
}

// K1/K3 swizzle (32 columns): bank image (2g+2t+2n1) = 16 even banks, 4 lanes
// each — the b64 floor (measured clean in K1).
__device__ __forceinline__ int PHY(int n, int g){
  return (n << 5) | ((g + n + (n >> 4)) & 31);
}

// K2 swizzle (16 columns, 32KB tile): every K2 pattern maps to
// (g + t + const) & 15 -> 16 distinct slots, 4 lanes/even-bank = b64 floor.
// (r7's PHY3 "+2n" doubled to bank-stride 4 in byte space -> 8-way; reverted.)
__device__ __forceinline__ int PHY16(int n, int gc){
  return (n << 4) | ((gc + n + (n >> 4)) & 15);
}

// Twiddle table: tw[k] = (cos, sin)(2*pi*k/256), double-computed, fp32-rounded.
__global__ void k0_twiddle(float2* __restrict__ tw){
  int k = threadIdx.x;
  double ang = 6.283185307179586476925286766559 * (double)k / 256.0;
  tw[k] = make_float2((float)cos(ang), (float)sin(ang));
}

// In-register 16-point FFT, SIGN=-1 forward / +1 inverse (unnormalized).
template<int SIGN>
__device__ __forceinline__ void fft16(cpx a[16]){
  cpx tmp;
  #define SW(i,j) tmp = a[i]; a[i] = a[j]; a[j] = tmp;
  SW(1,8) SW(2,4) SW(3,12) SW(5,10) SW(7,14) SW(11,13)
  #undef SW
  const float CT[8] = {1.f, 0.92387953251128674f, 0.70710678118654752f, 0.38268343236508977f,
                       0.f, -0.38268343236508977f, -0.70710678118654752f, -0.92387953251128674f};
  const float ST[8] = {0.f, 0.38268343236508977f, 0.70710678118654752f, 0.92387953251128674f,
                       1.f, 0.92387953251128674f, 0.70710678118654752f, 0.38268343236508977f};
  #pragma unroll
  for (int s = 1; s <= 4; ++s){
    const int m = 1 << s, half = m >> 1, str = 16 >> s;
    #pragma unroll
    for (int k = 0; k < 16; k += m){
      #pragma unroll
      for (int j = 0; j < half; ++j){
        cpx w; w.re = CT[j*str]; w.im = (float)SIGN * ST[j*str];
        cpx t = cmul(a[k+j+half], w);
        cpx u = a[k+j];
        a[k+j].re      = u.re + t.re; a[k+j].im      = u.im + t.im;
        a[k+j+half].re = u.re - t.re; a[k+j+half].im = u.im - t.im;
      }
    }
  }
}

// fft256_col on PHY (K1/K3).
template<int SIGN>
__device__ __forceinline__ void fft256_col(cpx* __restrict__ tile, int g, int t,
                                           const float2* __restrict__ tw){
  cpx a[16];
  #pragma unroll
  for (int n1 = 0; n1 < 16; ++n1) a[n1] = tile[PHY(16*n1 + t, g)];
  fft16<SIGN>(a);
  #pragma unroll
  for (int k1 = 1; k1 < 16; ++k1){
    float2 tv = tw[(t * k1) & 255];
    cpx w; w.re = tv.x; w.im = (SIGN < 0) ? -tv.y : tv.y;
    a[k1] = cmul(a[k1], w);
  }
  #pragma unroll
  for (int k1 = 0; k1 < 16; ++k1) tile[PHY(16*k1 + t, g)] = a[k1];
  __syncthreads();

  cpx b[16];
  #pragma unroll
  for (int n2 = 0; n2 < 16; ++n2) b[n2] = tile[PHY(16*t + n2, g)];
  fft16<SIGN>(b);
  __syncthreads();
  #pragma unroll
  for (int k2 = 0; k2 < 16; ++k2) tile[PHY(t + 16*k2, g)] = b[k2];
  __syncthreads();
}

// K1: rfft along b per (batch, a) row-tile; channel pairs packed as complex.
__global__ __launch_bounds__(512) void k1_rfft_b(const float* __restrict__ x,
                                                 float4* __restrict__ mid4,
                                                 const float2* __restrict__ tw){
  __shared__ cpx tile[256*32];
  const int tid = threadIdx.x;
  const int blk = blockIdx.x;            // bb*256 + a
  const int bb = blk >> 8, a = blk & 255;
  const int g = tid >> 4, t = tid & 15;

  const float4* src = (const float4*)(x + (size_t)blk * (NBD * NC));
  #pragma unroll
  for (int it = 0; it < 8; ++it){
    int idx = it*512 + tid;          // float4 index into [256][16] (contiguous)
    int j = idx >> 4, q = idx & 15;
    float4 v = src[idx];
    cpx p0; p0.re = v.x; p0.im = v.y;
    cpx p1; p1.re = v.z; p1.im = v.w;
    tile[PHY(j, 2*q)]   = p0;
    tile[PHY(j, 2*q+1)] = p1;
  }
  __syncthreads();

  fft256_col<-1>(tile, g, t, tw);

  for (int it = 0; it < 9; ++it){
    int idx = it*512 + tid;
    if (idx < NF*32){
      int k = idx >> 5, gg = idx & 31;
      cpx zk = tile[PHY(k, gg)];
      cpx zm = tile[PHY((256 - k) & 255, gg)];
      float4 o;
      o.x = 0.5f*(zk.re + zm.re);   // A.re
      o.y = 0.5f*(zk.im - zm.im);   // A.im
      o.z = 0.5f*(zk.im + zm.im);   // B.re
      o.w = 0.5f*(zm.re - zk.re);   // B.im
      mid4[(((size_t)bb*NF + k)*256 + a)*32 + gg] = o;
    }
  }
}

// K2 (wave-synchronous, 256 threads, 16 columns, 32KB LDS -> 5 blocks/CU):
// FFT along a, W-multiply, inverse FFT along a. Columns are wave-private
// (wave w owns g=4w..4w+3), so FFT exchanges need only wave_barrier.
// fwd-phase-B -> W-mul -> inv-phase-A fused in registers.
// Rows are 8 float4 wide with ROW STRIDE 32 float4 (other c-halves adjacent).
__global__ __launch_bounds__(256)
void k2_fft_a_mul(float2* __restrict__ mid2,
                  const float* __restrict__ wre,
                  const float* __restrict__ wim,
                  const float2* __restrict__ tw){
  __shared__ cpx tile[256*16];
  const int tid = threadIdx.x;
  int blk = blockIdx.x;                  // ((bb*129 + f)*4 + h)
  const int h = blk & 3; blk >>= 2;
  const int f = blk % NF, bb = blk / NF;
  const int g = tid >> 4, t = tid & 15;
  const int c0 = h * 16;

  float2* base = mid2 + ((size_t)bb*NF + f) * (256*64) + c0;
  const float4* base4 = (const float4*)base;

  // ---- stage: float4 loads (8/row, row stride 32) -> LDS (PHY16 swizzle)
  #pragma unroll
  for (int it = 0; it < 8; ++it){
    int idx = it*256 + tid;
    int r = idx >> 3, q = idx & 7;
    float4 v = base4[(size_t)r*32 + q];
    cpx p0; p0.re = v.x; p0.im = v.y;
    cpx p1; p1.re = v.z; p1.im = v.w;
    tile[PHY16(r, 2*q)]   = p0;
    tile[PHY16(r, 2*q+1)] = p1;
  }
  __syncthreads();

  // ---- forward phase A: stride-16 column read, fft16, twiddle
  cpx b[16];
  #pragma unroll
  for (int n1 = 0; n1 < 16; ++n1) b[n1] = tile[PHY16(16*n1 + t, g)];
  fft16<-1>(b);
  #pragma unroll
  for (int k1 = 1; k1 < 16; ++k1){
    float2 tv = tw[(t * k1) & 255];
    cpx w; w.re = tv.x; w.im = -tv.y;
    b[k1] = cmul(b[k1], w);
  }

  // ---- wave-local exchange (column is wave-private; DS pipe is in-order)
  #pragma unroll
  for (int k1 = 0; k1 < 16; ++k1) tile[PHY16(16*k1 + t, g)] = b[k1];
  __builtin_amdgcn_wave_barrier();
  #pragma unroll
  for (int n2 = 0; n2 < 16; ++n2) b[n2] = tile[PHY16(16*t + n2, g)];

  // ---- forward phase B -> S[t+16*k2] in registers
  fft16<-1>(b);

  // ---- spectral multiply (1/65536 folded), in registers
  #pragma unroll
  for (int k2 = 0; k2 < 16; ++k2){
    size_t wi = ((size_t)(t + 16*k2)*NF + f)*64 + (c0 + g);
    cpx w; w.re = wre[wi] * (1.0f/65536.0f); w.im = wim[wi] * (1.0f/65536.0f);
    b[k2] = cmul(b[k2], w);
  }

  // ---- inverse phase A (same stride-16 set), twiddle
  fft16<1>(b);
  #pragma unroll
  for (int k1 = 1; k1 < 16; ++k1){
    float2 tv = tw[(t * k1) & 255];
    cpx w; w.re = tv.x; w.im = tv.y;
    b[k1] = cmul(b[k1], w);
  }

  // ---- wave-local exchange 2
  __builtin_amdgcn_wave_barrier();
  #pragma unroll
  for (int k1 = 0; k1 < 16; ++k1) tile[PHY16(16*k1 + t, g)] = b[k1];
  __builtin_amdgcn_wave_barrier();
  #pragma unroll
  for (int n2 = 0; n2 < 16; ++n2) b[n2] = tile[PHY16(16*t + n2, g)];

  // ---- inverse phase B -> y[t+16*k2]; park in LDS for coalesced store
  fft16<1>(b);
  #pragma unroll
  for (int k2 = 0; k2 < 16; ++k2) tile[PHY16(t + 16*k2, g)] = b[k2];
  __syncthreads();

  // ---- float4 store back to mid (8/row, row stride 32), in place
  float4* ob = (float4*)base;
  #pragma unroll
  for (int it = 0; it < 8; ++it){
    int idx = it*256 + tid;
    int r = idx >> 3, q = idx & 7;
    cpx p0 = tile[PHY16(r, 2*q)];
    cpx p1 = tile[PHY16(r, 2*q+1)];
    float4 o; o.x = p0.re; o.y = p0.im; o.z = p1.re; o.w = p1.im;
    ob[(size_t)r*32 + q] = o;
  }
}

// K3: irfft along b per (batch, a). DC/Nyquist imaginary parts dropped (c2r).
__global__ __launch_bounds__(512) void k3_irfft_b(const float4* __restrict__ mid4,
                                                  float2* __restrict__ y2,
                                                  const float2* __restrict__ tw){
  __shared__ cpx tile[256*32];
  const int tid = threadIdx.x;
  const int blk = blockIdx.x;            // bb*256 + a
  const int bb = blk >> 8, a = blk & 255;
  const int g = tid >> 4, t = tid & 15;

  for (int it = 0; it < 9; ++it){
    int idx = it*512 + tid;
    if (idx < NF*32){
      int f = idx >> 5, gg = idx & 31;
      float4 v = mid4[(((size_t)bb*NF + f)*256 + a)*32 + gg];
      cpx sd;
      if (f == 0 || f == 128){
        sd.re = v.x;                 // Re(A); Im(A) dropped (c2r ignores it)
        sd.im = v.z;                 // Re(B); Im(B) dropped
      } else {
        sd.re = v.x - v.w; sd.im = v.y + v.z;   // S[f] = A + iB
      }
      tile[PHY(f, gg)] = sd;
      if (f >= 1 && f <= 127){
        cpx se; se.re = v.x + v.w; se.im = v.z - v.y;   // S[256-f] = conj(A)+i*conj(B)
        tile[PHY(256 - f, gg)] = se;
      }
    }
  }
  __syncthreads();

  fft256_col<+1>(tile, g, t, tw);

  float2* dst = y2 + (size_t)blk * (256*32);
  #pragma unroll
  for (int it = 0; it < 16; ++it){
    int idx = it*512 + tid;
    int n = idx >> 5, gg = idx & 31;
    cpx v = tile[PHY(n, gg)];
    float2 o; o.x = v.re; o.y = v.im;
    dst[(size_t)n*32 + gg] = o;
  }
}

extern "C" void kernel_launch(void* const* d_in, const int* in_sizes, int n_in,
                              void* d_out, int out_size, void* d_ws, size_t ws_size,
                              hipStream_t stream){
  const float* x   = (const float*)d_in[0];
  const float* wre = (const float*)d_in[1];
  const float* wim = (const float*)d_in[2];

  float2* tw = (float2*)d_ws;                    // 256 float2 = 2 KB
  float*  mid = (float*)d_ws + 512;              // NB*NF*256*64 complex = ~135.3 MB

  k0_twiddle  <<<1,   256, 0, stream>>>(tw);
  k1_rfft_b   <<<NB*NA,    512, 0, stream>>>(x, (float4*)mid, tw);
  k2_fft_a_mul<<<NB*NF*4,  256, 0, stream>>>((float2*)mid, wre, wim, tw);
  k3_irfft_b  <<<NB*NA,    512, 0, stream>>>((const float4*)mid, (float2*)d_out, tw);
}

// Round 9
// 219.893 us; speedup vs baseline: 1.1486x; 1.1486x over previous
//
#include <hip/hip_runtime.h>
#include <math.h>

#define NB 8
#define NA 256
#define NBD 256
#define NC 64
#define NF 129

struct alignas(8) cpx { float re, im; };

// packed fp16 complex <-> fp32, RNE scalar converts (v_cvt_f16_f32)
union H2U { uint u; _Float16 h[2]; };
__device__ __forceinline__ uint pkc(float re, float im){
  H2U x; x.h[0] = (_Float16)re; x.h[1] = (_Float16)im; return x.u;
}
__device__ __forceinline__ cpx unpkc(uint u){
  H2U x; x.u = u; cpx c; c.re = (float)x.h[0]; c.im = (float)x.h[1]; return c;
}

__device__ __forceinline__ cpx cmul(cpx a, cpx b){
  cpx r;
  r.re = fmaf(a.re, b.re, -(a.im * b.im));
  r.im = fmaf(a.re, b.im,  a.im * b.re);
  return r;
}

// K1/K3 swizzle (fp32 cpx tile, 32 columns).
__device__ __forceinline__ int PHY(int n, int g){
  return (n << 5) | ((g + n + (n >> 4)) & 31);
}

// K2 swizzle (packed-uint tile [256][32]): bank = col + 4*((n + n>>4)&7).
// Every K2 pattern (stage rows, stride-16 col, 16t+n2 row, t+16k park) maps
// 64 lanes onto banks with multiplicity <=2 (free, m136), and keeps
// 4-aligned col groups contiguous for uint4 stage/park.
__device__ __forceinline__ int PHYU(int n, int c){
  return (n << 5) | ((c + 4*((n + (n >> 4)) & 7)) & 31);
}

// Twiddle table: tw[k] = (cos, sin)(2*pi*k/256), double-computed, fp32-rounded.
__global__ void k0_twiddle(float2* __restrict__ tw){
  int k = threadIdx.x;
  double ang = 6.283185307179586476925286766559 * (double)k / 256.0;
  tw[k] = make_float2((float)cos(ang), (float)sin(ang));
}

// In-register 16-point FFT, SIGN=-1 forward / +1 inverse (unnormalized).
template<int SIGN>
__device__ __forceinline__ void fft16(cpx a[16]){
  cpx tmp;
  #define SW(i,j) tmp = a[i]; a[i] = a[j]; a[j] = tmp;
  SW(1,8) SW(2,4) SW(3,12) SW(5,10) SW(7,14) SW(11,13)
  #undef SW
  const float CT[8] = {1.f, 0.92387953251128674f, 0.70710678118654752f, 0.38268343236508977f,
                       0.f, -0.38268343236508977f, -0.70710678118654752f, -0.92387953251128674f};
  const float ST[8] = {0.f, 0.38268343236508977f, 0.70710678118654752f, 0.92387953251128674f,
                       1.f, 0.92387953251128674f, 0.70710678118654752f, 0.38268343236508977f};
  #pragma unroll
  for (int s = 1; s <= 4; ++s){
    const int m = 1 << s, half = m >> 1, str = 16 >> s;
    #pragma unroll
    for (int k = 0; k < 16; k += m){
      #pragma unroll
      for (int j = 0; j < half; ++j){
        cpx w; w.re = CT[j*str]; w.im = (float)SIGN * ST[j*str];
        cpx t = cmul(a[k+j+half], w);
        cpx u = a[k+j];
        a[k+j].re      = u.re + t.re; a[k+j].im      = u.im + t.im;
        a[k+j+half].re = u.re - t.re; a[k+j+half].im = u.im - t.im;
      }
    }
  }
}

// 256-pt FFT on fp32 tile column g (K1/K3). Columns are wave-private
// (wave w owns g=4w..4w+3), so intra-FFT exchanges need only wave_barrier;
// ends with a full __syncthreads before cross-wave consumption.
template<int SIGN>
__device__ __forceinline__ void fft256_col(cpx* __restrict__ tile, int g, int t,
                                           const float2* __restrict__ tw){
  cpx a[16];
  #pragma unroll
  for (int n1 = 0; n1 < 16; ++n1) a[n1] = tile[PHY(16*n1 + t, g)];
  fft16<SIGN>(a);
  #pragma unroll
  for (int k1 = 1; k1 < 16; ++k1){
    float2 tv = tw[(t * k1) & 255];
    cpx w; w.re = tv.x; w.im = (SIGN < 0) ? -tv.y : tv.y;
    a[k1] = cmul(a[k1], w);
  }
  #pragma unroll
  for (int k1 = 0; k1 < 16; ++k1) tile[PHY(16*k1 + t, g)] = a[k1];
  __builtin_amdgcn_wave_barrier();

  cpx b[16];
  #pragma unroll
  for (int n2 = 0; n2 < 16; ++n2) b[n2] = tile[PHY(16*t + n2, g)];
  fft16<SIGN>(b);
  __builtin_amdgcn_wave_barrier();
  #pragma unroll
  for (int k2 = 0; k2 < 16; ++k2) tile[PHY(t + 16*k2, g)] = b[k2];
  __syncthreads();
}

// mid layout (packed fp16 cpx, uint each): [bb][f][h][a][cc], cc in 0..31,
// global channel = h*32 + cc. Each K2 block's tile is contiguous 32KB.

// K1: rfft along b per (batch, a) row-tile; channel pairs packed as complex.
__global__ __launch_bounds__(512) void k1_rfft_b(const float* __restrict__ x,
                                                 uint2* __restrict__ mid_p2,
                                                 const float2* __restrict__ tw){
  __shared__ cpx tile[256*32];
  const int tid = threadIdx.x;
  const int blk = blockIdx.x;            // bb*256 + a
  const int bb = blk >> 8, a = blk & 255;
  const int g = tid >> 4, t = tid & 15;

  const float4* src = (const float4*)(x + (size_t)blk * (NBD * NC));
  #pragma unroll
  for (int it = 0; it < 8; ++it){
    int idx = it*512 + tid;          // float4 index into [256][16] (contiguous)
    int j = idx >> 4, q = idx & 15;
    float4 v = src[idx];
    cpx p0; p0.re = v.x; p0.im = v.y;
    cpx p1; p1.re = v.z; p1.im = v.w;
    tile[PHY(j, 2*q)]   = p0;
    tile[PHY(j, 2*q+1)] = p1;
  }
  __syncthreads();

  fft256_col<-1>(tile, g, t, tw);

  for (int it = 0; it < 9; ++it){
    int idx = it*512 + tid;
    if (idx < NF*32){
      int k = idx >> 5, gg = idx & 31;
      cpx zk = tile[PHY(k, gg)];
      cpx zm = tile[PHY((256 - k) & 255, gg)];
      float Ar = 0.5f*(zk.re + zm.re);
      float Ai = 0.5f*(zk.im - zm.im);
      float Br = 0.5f*(zk.im + zm.im);
      float Bi = 0.5f*(zm.re - zk.re);
      int hh = gg >> 4;
      size_t o = ((((size_t)bb*NF + k)*2 + hh)*256 + a)*16 + (gg & 15);
      uint2 pv; pv.x = pkc(Ar, Ai); pv.y = pkc(Br, Bi);
      mid_p2[o] = pv;
    }
  }
}

// K2 (wave-sync, packed-fp16 LDS tile 32KB): FFT along a, W-mul, iFFT along a.
// NO 1/65536 here — post-K2 values would be fp16-denormal; scale lives in K3.
__global__ __launch_bounds__(512)
void k2_fft_a_mul(uint* __restrict__ mid_u,
                  const float* __restrict__ wre,
                  const float* __restrict__ wim,
                  const float2* __restrict__ tw){
  __shared__ uint tile_u[256*32];
  const int tid = threadIdx.x;
  int blk = blockIdx.x;                  // ((bb*129 + f)*2 + h)
  const int h = blk & 1; blk >>= 1;
  const int f = blk % NF, bb = blk / NF;
  const int g = tid >> 4, t = tid & 15;  // col g wave-private (wave = tid>>6)

  uint* base_u = mid_u + ((((size_t)bb*NF + f)*2 + h) << 13);   // *256*32

  // ---- stage: contiguous uint4 loads -> LDS, stays packed (no cvt)
  const uint4* base4 = (const uint4*)base_u;
  #pragma unroll
  for (int it = 0; it < 4; ++it){
    int idx = it*512 + tid;
    int r = idx >> 3, q = idx & 7;
    uint4 v = base4[idx];
    int koff = (r + (r >> 4)) & 7;
    *(uint4*)&tile_u[(r << 5) | (4*((q + koff) & 7))] = v;
  }
  __syncthreads();

  // ---- forward phase A: stride-16 col read (2-way banks), fft16, twiddle
  cpx b[16];
  #pragma unroll
  for (int n1 = 0; n1 < 16; ++n1) b[n1] = unpkc(tile_u[PHYU(16*n1 + t, g)]);
  fft16<-1>(b);
  #pragma unroll
  for (int k1 = 1; k1 < 16; ++k1){
    float2 tv = tw[(t * k1) & 255];
    cpx w; w.re = tv.x; w.im = -tv.y;
    b[k1] = cmul(b[k1], w);
  }

  // ---- wave-local exchange 1
  #pragma unroll
  for (int k1 = 0; k1 < 16; ++k1) tile_u[PHYU(16*k1 + t, g)] = pkc(b[k1].re, b[k1].im);
  __builtin_amdgcn_wave_barrier();
  #pragma unroll
  for (int n2 = 0; n2 < 16; ++n2) b[n2] = unpkc(tile_u[PHYU(16*t + n2, g)]);

  // ---- forward phase B -> S[t+16*k2] in registers
  fft16<-1>(b);

  // ---- spectral multiply (unscaled), in registers
  const int c = h*32 + g;
  #pragma unroll
  for (int k2 = 0; k2 < 16; ++k2){
    size_t wi = ((size_t)(t + 16*k2)*NF + f)*64 + c;
    cpx w; w.re = wre[wi]; w.im = wim[wi];
    b[k2] = cmul(b[k2], w);
  }

  // ---- inverse phase A (same stride-16 set), twiddle
  fft16<1>(b);
  #pragma unroll
  for (int k1 = 1; k1 < 16; ++k1){
    float2 tv = tw[(t * k1) & 255];
    cpx w; w.re = tv.x; w.im = tv.y;
    b[k1] = cmul(b[k1], w);
  }

  // ---- wave-local exchange 2
  __builtin_amdgcn_wave_barrier();
  #pragma unroll
  for (int k1 = 0; k1 < 16; ++k1) tile_u[PHYU(16*k1 + t, g)] = pkc(b[k1].re, b[k1].im);
  __builtin_amdgcn_wave_barrier();
  #pragma unroll
  for (int n2 = 0; n2 < 16; ++n2) b[n2] = unpkc(tile_u[PHYU(16*t + n2, g)]);

  // ---- inverse phase B; park packed for coalesced store
  fft16<1>(b);
  #pragma unroll
  for (int k2 = 0; k2 < 16; ++k2) tile_u[PHYU(t + 16*k2, g)] = pkc(b[k2].re, b[k2].im);
  __syncthreads();

  // ---- contiguous uint4 store back (in place)
  uint4* ob = (uint4*)base_u;
  #pragma unroll
  for (int it = 0; it < 4; ++it){
    int idx = it*512 + tid;
    int r = idx >> 3, q = idx & 7;
    int koff = (r + (r >> 4)) & 7;
    ob[idx] = *(const uint4*)&tile_u[(r << 5) | (4*((q + koff) & 7))];
  }
}

// K3: irfft along b per (batch, a). DC/Nyquist imaginary parts dropped (c2r).
// Applies the 1/(a*b) normalization at the output store.
__global__ __launch_bounds__(512) void k3_irfft_b(const uint2* __restrict__ mid_p2,
                                                  float2* __restrict__ y2,
                                                  const float2* __restrict__ tw){
  __shared__ cpx tile[256*32];
  const int tid = threadIdx.x;
  const int blk = blockIdx.x;            // bb*256 + a
  const int bb = blk >> 8, a = blk & 255;
  const int g = tid >> 4, t = tid & 15;

  for (int it = 0; it < 9; ++it){
    int idx = it*512 + tid;
    if (idx < NF*32){
      int f = idx >> 5, gg = idx & 31;
      int hh = gg >> 4;
      size_t o = ((((size_t)bb*NF + f)*2 + hh)*256 + a)*16 + (gg & 15);
      uint2 pv = mid_p2[o];
      cpx A = unpkc(pv.x), B = unpkc(pv.y);
      cpx sd;
      if (f == 0 || f == 128){
        sd.re = A.re;                // Im(A), Im(B) dropped (c2r semantics)
        sd.im = B.re;
      } else {
        sd.re = A.re - B.im; sd.im = A.im + B.re;       // S[f] = A + iB
      }
      tile[PHY(f, gg)] = sd;
      if (f >= 1 && f <= 127){
        cpx se; se.re = A.re + B.im; se.im = B.re - A.im; // S[256-f]
        tile[PHY(256 - f, gg)] = se;
      }
    }
  }
  __syncthreads();

  fft256_col<+1>(tile, g, t, tw);

  const float SC = 1.52587890625e-05f;   // 1/65536
  float2* dst = y2 + (size_t)blk * (256*32);
  #pragma unroll
  for (int it = 0; it < 16; ++it){
    int idx = it*512 + tid;
    int n = idx >> 5, gg = idx & 31;
    cpx v = tile[PHY(n, gg)];
    float2 o; o.x = v.re * SC; o.y = v.im * SC;
    dst[(size_t)n*32 + gg] = o;
  }
}

extern "C" void kernel_launch(void* const* d_in, const int* in_sizes, int n_in,
                              void* d_out, int out_size, void* d_ws, size_t ws_size,
                              hipStream_t stream){
  const float* x   = (const float*)d_in[0];
  const float* wre = (const float*)d_in[1];
  const float* wim = (const float*)d_in[2];

  float2* tw   = (float2*)d_ws;                  // 256 float2 = 2 KB
  uint*   midu = (uint*)d_ws + 512;              // packed fp16 mid, ~67.6 MB

  k0_twiddle  <<<1,   256, 0, stream>>>(tw);
  k1_rfft_b   <<<NB*NA,    512, 0, stream>>>(x, (uint2*)midu, tw);
  k2_fft_a_mul<<<NB*NF*2,  512, 0, stream>>>(midu, wre, wim, tw);
  k3_irfft_b  <<<NB*NA,    512, 0, stream>>>((const uint2*)midu, (float2*)d_out, tw);
}

// Round 10
// 211.716 us; speedup vs baseline: 1.1929x; 1.0386x over previous
//
#include <hip/hip_runtime.h>
#include <math.h>

#define NB 8
#define NA 256
#define NBD 256
#define NC 64
#define NF 129

struct alignas(8) cpx { float re, im; };

// packed fp16 complex <-> fp32
union H2U { uint u; _Float16 h[2]; };
__device__ __forceinline__ uint pkc(float re, float im){
  H2U x; x.h[0] = (_Float16)re; x.h[1] = (_Float16)im; return x.u;
}
__device__ __forceinline__ cpx unpkc(uint u){
  H2U x; x.u = u; cpx c; c.re = (float)x.h[0]; c.im = (float)x.h[1]; return c;
}

__device__ __forceinline__ cpx cmul(cpx a, cpx b){
  cpx r;
  r.re = fmaf(a.re, b.re, -(a.im * b.im));
  r.im = fmaf(a.re, b.im,  a.im * b.re);
  return r;
}

// K1/K3 swizzle (fp32 cpx tile, 32 columns).
__device__ __forceinline__ int PHY(int n, int g){
  return (n << 5) | ((g + n + (n >> 4)) & 31);
}

// K2 swizzle: logical (r,c), r in 0..255, c in 0..15 (uints); physical tile is
// [128][32] uints. bit4 of the phys col = (r&1)^(r>>4&1); bits2-3 XORed with
// ((r>>1)+(r>>5))&3. Independent row-bit sources make ALL six access patterns
// (stage rows, stride-16 col read, both exchange writes/reads, park) <=2-way.
// Low 2 bits of c untouched -> uint4 ops stay aligned.
__device__ __forceinline__ int PHYS(int r, int c){
  int p = ((r & 1) ^ ((r >> 4) & 1)) << 4;
  int s = (((r >> 1) + (r >> 5)) & 3) << 2;
  return ((r >> 1) << 5) | p | ((c & 12) ^ s) | (c & 3);
}

// Twiddle table: tw[k] = (cos, sin)(2*pi*k/256), double-computed, fp32-rounded.
__global__ void k0_twiddle(float2* __restrict__ tw){
  int k = threadIdx.x;
  double ang = 6.283185307179586476925286766559 * (double)k / 256.0;
  tw[k] = make_float2((float)cos(ang), (float)sin(ang));
}

// In-register 16-point FFT, SIGN=-1 forward / +1 inverse (unnormalized).
template<int SIGN>
__device__ __forceinline__ void fft16(cpx a[16]){
  cpx tmp;
  #define SW(i,j) tmp = a[i]; a[i] = a[j]; a[j] = tmp;
  SW(1,8) SW(2,4) SW(3,12) SW(5,10) SW(7,14) SW(11,13)
  #undef SW
  const float CT[8] = {1.f, 0.92387953251128674f, 0.70710678118654752f, 0.38268343236508977f,
                       0.f, -0.38268343236508977f, -0.70710678118654752f, -0.92387953251128674f};
  const float ST[8] = {0.f, 0.38268343236508977f, 0.70710678118654752f, 0.92387953251128674f,
                       1.f, 0.92387953251128674f, 0.70710678118654752f, 0.38268343236508977f};
  #pragma unroll
  for (int s = 1; s <= 4; ++s){
    const int m = 1 << s, half = m >> 1, str = 16 >> s;
    #pragma unroll
    for (int k = 0; k < 16; k += m){
      #pragma unroll
      for (int j = 0; j < half; ++j){
        cpx w; w.re = CT[j*str]; w.im = (float)SIGN * ST[j*str];
        cpx t = cmul(a[k+j+half], w);
        cpx u = a[k+j];
        a[k+j].re      = u.re + t.re; a[k+j].im      = u.im + t.im;
        a[k+j+half].re = u.re - t.re; a[k+j+half].im = u.im - t.im;
      }
    }
  }
}

// 256-pt FFT on fp32 tile column g (K1/K3). Columns are wave-private
// (wave w owns g=4w..4w+3): intra-FFT exchanges need only wave_barrier.
template<int SIGN>
__device__ __forceinline__ void fft256_col(cpx* __restrict__ tile, int g, int t,
                                           const float2* __restrict__ tw){
  cpx a[16];
  #pragma unroll
  for (int n1 = 0; n1 < 16; ++n1) a[n1] = tile[PHY(16*n1 + t, g)];
  fft16<SIGN>(a);
  #pragma unroll
  for (int k1 = 1; k1 < 16; ++k1){
    float2 tv = tw[(t * k1) & 255];
    cpx w; w.re = tv.x; w.im = (SIGN < 0) ? -tv.y : tv.y;
    a[k1] = cmul(a[k1], w);
  }
  #pragma unroll
  for (int k1 = 0; k1 < 16; ++k1) tile[PHY(16*k1 + t, g)] = a[k1];
  __builtin_amdgcn_wave_barrier();

  cpx b[16];
  #pragma unroll
  for (int n2 = 0; n2 < 16; ++n2) b[n2] = tile[PHY(16*t + n2, g)];
  fft16<SIGN>(b);
  __builtin_amdgcn_wave_barrier();
  #pragma unroll
  for (int k2 = 0; k2 < 16; ++k2) tile[PHY(t + 16*k2, g)] = b[k2];
  __syncthreads();
}

// mid layout (packed fp16 cpx, uint each): [bb][f][h:4][a:256][c:16] — each
// K2 block's tile is one fully-contiguous 16KB slab.

// K1: rfft along b per (batch, a) row-tile; channel pairs packed as complex.
__global__ __launch_bounds__(512) void k1_rfft_b(const float* __restrict__ x,
                                                 uint2* __restrict__ mid_p2,
                                                 const float2* __restrict__ tw){
  __shared__ cpx tile[256*32];
  const int tid = threadIdx.x;
  const int blk = blockIdx.x;            // bb*256 + a
  const int bb = blk >> 8, a = blk & 255;
  const int g = tid >> 4, t = tid & 15;

  const float4* src = (const float4*)(x + (size_t)blk * (NBD * NC));
  #pragma unroll
  for (int it = 0; it < 8; ++it){
    int idx = it*512 + tid;          // float4 index into [256][16] (contiguous)
    int j = idx >> 4, q = idx & 15;
    float4 v = src[idx];
    cpx p0; p0.re = v.x; p0.im = v.y;
    cpx p1; p1.re = v.z; p1.im = v.w;
    tile[PHY(j, 2*q)]   = p0;
    tile[PHY(j, 2*q+1)] = p1;
  }
  __syncthreads();

  fft256_col<-1>(tile, g, t, tw);

  for (int it = 0; it < 9; ++it){
    int idx = it*512 + tid;
    if (idx < NF*32){
      int k = idx >> 5, gg = idx & 31;
      cpx zk = tile[PHY(k, gg)];
      cpx zm = tile[PHY((256 - k) & 255, gg)];
      float Ar = 0.5f*(zk.re + zm.re);
      float Ai = 0.5f*(zk.im - zm.im);
      float Br = 0.5f*(zk.im + zm.im);
      float Bi = 0.5f*(zm.re - zk.re);
      // channels 2gg,2gg+1 -> h = gg>>3, slot = gg&7 (uint2 = both channels)
      size_t o = ((((size_t)bb*NF + k)*4 + (gg >> 3))*256 + a)*8 + (gg & 7);
      uint2 pv; pv.x = pkc(Ar, Ai); pv.y = pkc(Br, Bi);
      mid_p2[o] = pv;
    }
  }
}

// K2 (wave-sync, 256 thr, 16 channels, 16KB contiguous packed tile,
// 8 blocks/CU): FFT along a, W-mul, iFFT along a. No 1/65536 here (fp16
// denormals); scale lives in K3. fwd-B -> W-mul -> inv-A fused in registers.
__global__ __launch_bounds__(256)
void k2_fft_a_mul(uint* __restrict__ mid_u,
                  const float* __restrict__ wre,
                  const float* __restrict__ wim,
                  const float2* __restrict__ tw){
  __shared__ uint tile_u[256*16];
  const int tid = threadIdx.x;
  int blk = blockIdx.x;                  // ((bb*129 + f)*4 + h)
  const int h = blk & 3; blk >>= 2;
  const int f = blk % NF, bb = blk / NF;
  const int g = tid >> 4, t = tid & 15;  // wave w owns g in {4w..4w+3}

  uint* base_u = mid_u + ((((size_t)bb*NF + f)*4 + h) << 12);   // *4096 uints

  // ---- stage: 4 x uint4 per thread, fully contiguous 16KB
  const uint4* base4 = (const uint4*)base_u;
  #pragma unroll
  for (int it = 0; it < 4; ++it){
    int idx = it*256 + tid;
    int r = idx >> 2, q = idx & 3;
    uint4 v = base4[idx];
    *(uint4*)&tile_u[PHYS(r, 4*q)] = v;
  }
  __syncthreads();

  // ---- forward phase A: stride-16 col read (2-way banks), fft16, twiddle
  cpx b[16];
  #pragma unroll
  for (int n1 = 0; n1 < 16; ++n1) b[n1] = unpkc(tile_u[PHYS(16*n1 + t, g)]);
  fft16<-1>(b);
  #pragma unroll
  for (int k1 = 1; k1 < 16; ++k1){
    float2 tv = tw[(t * k1) & 255];
    cpx w; w.re = tv.x; w.im = -tv.y;
    b[k1] = cmul(b[k1], w);
  }

  // ---- wave-local exchange 1 (column wave-private; DS pipe in-order)
  #pragma unroll
  for (int k1 = 0; k1 < 16; ++k1) tile_u[PHYS(16*k1 + t, g)] = pkc(b[k1].re, b[k1].im);
  __builtin_amdgcn_wave_barrier();
  #pragma unroll
  for (int n2 = 0; n2 < 16; ++n2) b[n2] = unpkc(tile_u[PHYS(16*t + n2, g)]);

  // ---- forward phase B -> S[t+16*k2] in registers
  fft16<-1>(b);

  // ---- spectral multiply (unscaled), in registers
  const int c = h*16 + g;
  #pragma unroll
  for (int k2 = 0; k2 < 16; ++k2){
    size_t wi = ((size_t)(t + 16*k2)*NF + f)*64 + c;
    cpx w; w.re = wre[wi]; w.im = wim[wi];
    b[k2] = cmul(b[k2], w);
  }

  // ---- inverse phase A (same stride-16 set), twiddle
  fft16<1>(b);
  #pragma unroll
  for (int k1 = 1; k1 < 16; ++k1){
    float2 tv = tw[(t * k1) & 255];
    cpx w; w.re = tv.x; w.im = tv.y;
    b[k1] = cmul(b[k1], w);
  }

  // ---- wave-local exchange 2
  __builtin_amdgcn_wave_barrier();
  #pragma unroll
  for (int k1 = 0; k1 < 16; ++k1) tile_u[PHYS(16*k1 + t, g)] = pkc(b[k1].re, b[k1].im);
  __builtin_amdgcn_wave_barrier();
  #pragma unroll
  for (int n2 = 0; n2 < 16; ++n2) b[n2] = unpkc(tile_u[PHYS(16*t + n2, g)]);

  // ---- inverse phase B; park packed for coalesced store
  fft16<1>(b);
  #pragma unroll
  for (int k2 = 0; k2 < 16; ++k2) tile_u[PHYS(t + 16*k2, g)] = pkc(b[k2].re, b[k2].im);
  __syncthreads();

  // ---- contiguous uint4 store back (in place)
  uint4* ob = (uint4*)base_u;
  #pragma unroll
  for (int it = 0; it < 4; ++it){
    int idx = it*256 + tid;
    int r = idx >> 2, q = idx & 3;
    ob[idx] = *(const uint4*)&tile_u[PHYS(r, 4*q)];
  }
}

// K3: irfft along b per (batch, a). DC/Nyquist imaginary parts dropped (c2r).
// Applies the 1/(a*b) normalization at the output store.
__global__ __launch_bounds__(512) void k3_irfft_b(const uint2* __restrict__ mid_p2,
                                                  float2* __restrict__ y2,
                                                  const float2* __restrict__ tw){
  __shared__ cpx tile[256*32];
  const int tid = threadIdx.x;
  const int blk = blockIdx.x;            // bb*256 + a
  const int bb = blk >> 8, a = blk & 255;
  const int g = tid >> 4, t = tid & 15;

  for (int it = 0; it < 9; ++it){
    int idx = it*512 + tid;
    if (idx < NF*32){
      int f = idx >> 5, gg = idx & 31;
      size_t o = ((((size_t)bb*NF + f)*4 + (gg >> 3))*256 + a)*8 + (gg & 7);
      uint2 pv = mid_p2[o];
      cpx A = unpkc(pv.x), B = unpkc(pv.y);
      cpx sd;
      if (f == 0 || f == 128){
        sd.re = A.re;                // Im(A), Im(B) dropped (c2r semantics)
        sd.im = B.re;
      } else {
        sd.re = A.re - B.im; sd.im = A.im + B.re;       // S[f] = A + iB
      }
      tile[PHY(f, gg)] = sd;
      if (f >= 1 && f <= 127){
        cpx se; se.re = A.re + B.im; se.im = B.re - A.im; // S[256-f]
        tile[PHY(256 - f, gg)] = se;
      }
    }
  }
  __syncthreads();

  fft256_col<+1>(tile, g, t, tw);

  const float SC = 1.52587890625e-05f;   // 1/65536
  float2* dst = y2 + (size_t)blk * (256*32);
  #pragma unroll
  for (int it = 0; it < 16; ++it){
    int idx = it*512 + tid;
    int n = idx >> 5, gg = idx & 31;
    cpx v = tile[PHY(n, gg)];
    float2 o; o.x = v.re * SC; o.y = v.im * SC;
    dst[(size_t)n*32 + gg] = o;
  }
}

extern "C" void kernel_launch(void* const* d_in, const int* in_sizes, int n_in,
                              void* d_out, int out_size, void* d_ws, size_t ws_size,
                              hipStream_t stream){
  const float* x   = (const float*)d_in[0];
  const float* wre = (const float*)d_in[1];
  const float* wim = (const float*)d_in[2];

  float2* tw   = (float2*)d_ws;                  // 256 float2 = 2 KB
  uint*   midu = (uint*)d_ws + 512;              // packed fp16 mid, ~67.7 MB

  k0_twiddle  <<<1,   256, 0, stream>>>(tw);
  k1_rfft_b   <<<NB*NA,    512, 0, stream>>>(x, (uint2*)midu, tw);
  k2_fft_a_mul<<<NB*NF*4,  256, 0, stream>>>(midu, wre, wim, tw);
  k3_irfft_b  <<<NB*NA,    512, 0, stream>>>((const uint2*)midu, (float2*)d_out, tw);
}

// Round 11
// 188.686 us; speedup vs baseline: 1.3385x; 1.1221x over previous
//
#include <hip/hip_runtime.h>
#include <math.h>

#define NB 8
#define NA 256
#define NBD 256
#define NC 64
#define NF 129

struct alignas(8) cpx { float re, im; };

// packed fp16 complex <-> fp32
union H2U { uint u; _Float16 h[2]; };
__device__ __forceinline__ uint pkc(float re, float im){
  H2U x; x.h[0] = (_Float16)re; x.h[1] = (_Float16)im; return x.u;
}
__device__ __forceinline__ cpx unpkc(uint u){
  H2U x; x.u = u; cpx c; c.re = (float)x.h[0]; c.im = (float)x.h[1]; return c;
}

__device__ __forceinline__ cpx cmul(cpx a, cpx b){
  cpx r;
  r.re = fmaf(a.re, b.re, -(a.im * b.im));
  r.im = fmaf(a.re, b.im,  a.im * b.re);
  return r;
}

// K1/K3 swizzle (fp32 cpx tile, 32 columns).
__device__ __forceinline__ int PHY(int n, int g){
  return (n << 5) | ((g + n + (n >> 4)) & 31);
}

// K2 swizzle: logical (r,c), r in 0..255, c in 0..15 (uints); physical tile
// [128][32] uints. Independent row-bit sources -> <=2-way on all six access
// patterns; low 2 bits of c untouched so uint4 ops stay aligned.
__device__ __forceinline__ int PHYS(int r, int c){
  int p = ((r & 1) ^ ((r >> 4) & 1)) << 4;
  int s = (((r >> 1) + (r >> 5)) & 3) << 2;
  return ((r >> 1) << 5) | p | ((c & 12) ^ s) | (c & 3);
}

// Twiddle table: tw[k] = (cos, sin)(2*pi*k/256), double-computed, fp32-rounded.
__global__ void k0_twiddle(float2* __restrict__ tw){
  int k = threadIdx.x;
  double ang = 6.283185307179586476925286766559 * (double)k / 256.0;
  tw[k] = make_float2((float)cos(ang), (float)sin(ang));
}

// k0w: repack W -> Wp[f][h][ka:256][c:16] packed-fp16, pre-scaled by 256
// (unscaled W sigma ~1.5e-5 sits in fp16-subnormal range; x256 normalizes).
// One contiguous 16KB slab per K2 block. 1/256 is folded into K3's SC.
__global__ __launch_bounds__(256) void k0w_pack(const float* __restrict__ wre,
                                                const float* __restrict__ wim,
                                                uint* __restrict__ wp){
  const int blk = blockIdx.x;            // f*4 + h
  const int f = blk >> 2, h = blk & 3;
  const int tid = threadIdx.x;
  const int c = tid & 15, kb = tid >> 4;
  uint* dst = wp + (size_t)blk * 4096;
  #pragma unroll
  for (int it = 0; it < 16; ++it){
    int ka = kb + 16*it;
    size_t src = ((size_t)ka*NF + f)*64 + h*16 + c;
    dst[ka*16 + c] = pkc(wre[src] * 256.0f, wim[src] * 256.0f);
  }
}

// In-register 16-point FFT, SIGN=-1 forward / +1 inverse (unnormalized).
template<int SIGN>
__device__ __forceinline__ void fft16(cpx a[16]){
  cpx tmp;
  #define SW(i,j) tmp = a[i]; a[i] = a[j]; a[j] = tmp;
  SW(1,8) SW(2,4) SW(3,12) SW(5,10) SW(7,14) SW(11,13)
  #undef SW
  const float CT[8] = {1.f, 0.92387953251128674f, 0.70710678118654752f, 0.38268343236508977f,
                       0.f, -0.38268343236508977f, -0.70710678118654752f, -0.92387953251128674f};
  const float ST[8] = {0.f, 0.38268343236508977f, 0.70710678118654752f, 0.92387953251128674f,
                       1.f, 0.92387953251128674f, 0.70710678118654752f, 0.38268343236508977f};
  #pragma unroll
  for (int s = 1; s <= 4; ++s){
    const int m = 1 << s, half = m >> 1, str = 16 >> s;
    #pragma unroll
    for (int k = 0; k < 16; k += m){
      #pragma unroll
      for (int j = 0; j < half; ++j){
        cpx w; w.re = CT[j*str]; w.im = (float)SIGN * ST[j*str];
        cpx t = cmul(a[k+j+half], w);
        cpx u = a[k+j];
        a[k+j].re      = u.re + t.re; a[k+j].im      = u.im + t.im;
        a[k+j+half].re = u.re - t.re; a[k+j+half].im = u.im - t.im;
      }
    }
  }
}

// 256-pt FFT on fp32 tile column g (K1/K3). Columns are wave-private
// (wave w owns g=4w..4w+3): intra-FFT exchanges need only wave_barrier.
template<int SIGN>
__device__ __forceinline__ void fft256_col(cpx* __restrict__ tile, int g, int t,
                                           const float2* __restrict__ tw){
  cpx a[16];
  #pragma unroll
  for (int n1 = 0; n1 < 16; ++n1) a[n1] = tile[PHY(16*n1 + t, g)];
  fft16<SIGN>(a);
  #pragma unroll
  for (int k1 = 1; k1 < 16; ++k1){
    float2 tv = tw[(t * k1) & 255];
    cpx w; w.re = tv.x; w.im = (SIGN < 0) ? -tv.y : tv.y;
    a[k1] = cmul(a[k1], w);
  }
  #pragma unroll
  for (int k1 = 0; k1 < 16; ++k1) tile[PHY(16*k1 + t, g)] = a[k1];
  __builtin_amdgcn_wave_barrier();

  cpx b[16];
  #pragma unroll
  for (int n2 = 0; n2 < 16; ++n2) b[n2] = tile[PHY(16*t + n2, g)];
  fft16<SIGN>(b);
  __builtin_amdgcn_wave_barrier();
  #pragma unroll
  for (int k2 = 0; k2 < 16; ++k2) tile[PHY(t + 16*k2, g)] = b[k2];
  __syncthreads();
}

// mid layout (packed fp16 cpx, uint each): [bb][f][h:4][a:256][c:16] — each
// K2 block's tile is one fully-contiguous 16KB slab.

// K1: rfft along b per (batch, a) row-tile; channel pairs packed as complex.
__global__ __launch_bounds__(512) void k1_rfft_b(const float* __restrict__ x,
                                                 uint2* __restrict__ mid_p2,
                                                 const float2* __restrict__ tw){
  __shared__ cpx tile[256*32];
  const int tid = threadIdx.x;
  const int blk = blockIdx.x;            // bb*256 + a
  const int bb = blk >> 8, a = blk & 255;
  const int g = tid >> 4, t = tid & 15;

  const float4* src = (const float4*)(x + (size_t)blk * (NBD * NC));
  #pragma unroll
  for (int it = 0; it < 8; ++it){
    int idx = it*512 + tid;          // float4 index into [256][16] (contiguous)
    int j = idx >> 4, q = idx & 15;
    float4 v = src[idx];
    cpx p0; p0.re = v.x; p0.im = v.y;
    cpx p1; p1.re = v.z; p1.im = v.w;
    tile[PHY(j, 2*q)]   = p0;
    tile[PHY(j, 2*q+1)] = p1;
  }
  __syncthreads();

  fft256_col<-1>(tile, g, t, tw);

  for (int it = 0; it < 9; ++it){
    int idx = it*512 + tid;
    if (idx < NF*32){
      int k = idx >> 5, gg = idx & 31;
      cpx zk = tile[PHY(k, gg)];
      cpx zm = tile[PHY((256 - k) & 255, gg)];
      float Ar = 0.5f*(zk.re + zm.re);
      float Ai = 0.5f*(zk.im - zm.im);
      float Br = 0.5f*(zk.im + zm.im);
      float Bi = 0.5f*(zm.re - zk.re);
      size_t o = ((((size_t)bb*NF + k)*4 + (gg >> 3))*256 + a)*8 + (gg & 7);
      uint2 pv; pv.x = pkc(Ar, Ai); pv.y = pkc(Br, Bi);
      mid_p2[o] = pv;
    }
  }
}

// K2 (wave-sync, 256 thr, 16 channels, 16KB contiguous packed tile):
// FFT along a, W-mul (from contiguous Wp slab), iFFT along a.
// f-major grid so the 8 bb-blocks sharing one Wp slab run temporally close.
__global__ __launch_bounds__(256)
void k2_fft_a_mul(uint* __restrict__ mid_u,
                  const uint* __restrict__ wp,
                  const float2* __restrict__ tw){
  __shared__ uint tile_u[256*16];
  const int tid = threadIdx.x;
  const int blk = blockIdx.x;            // f*32 + bb*4 + h
  const int f = blk >> 5;
  const int bb = (blk >> 2) & 7, h = blk & 3;
  const int g = tid >> 4, t = tid & 15;  // wave w owns g in {4w..4w+3}

  uint* base_u = mid_u + ((((size_t)bb*NF + f)*4 + h) << 12);   // *4096 uints
  const uint* wslab = wp + ((size_t)(f*4 + h) << 12);

  // ---- stage: 4 x uint4 per thread, fully contiguous 16KB
  const uint4* base4 = (const uint4*)base_u;
  #pragma unroll
  for (int it = 0; it < 4; ++it){
    int idx = it*256 + tid;
    int r = idx >> 2, q = idx & 3;
    uint4 v = base4[idx];
    *(uint4*)&tile_u[PHYS(r, 4*q)] = v;
  }
  __syncthreads();

  // ---- forward phase A: stride-16 col read (2-way banks), fft16, twiddle
  cpx b[16];
  #pragma unroll
  for (int n1 = 0; n1 < 16; ++n1) b[n1] = unpkc(tile_u[PHYS(16*n1 + t, g)]);
  fft16<-1>(b);
  #pragma unroll
  for (int k1 = 1; k1 < 16; ++k1){
    float2 tv = tw[(t * k1) & 255];
    cpx w; w.re = tv.x; w.im = -tv.y;
    b[k1] = cmul(b[k1], w);
  }

  // ---- wave-local exchange 1 (column wave-private; DS pipe in-order)
  #pragma unroll
  for (int k1 = 0; k1 < 16; ++k1) tile_u[PHYS(16*k1 + t, g)] = pkc(b[k1].re, b[k1].im);
  __builtin_amdgcn_wave_barrier();
  #pragma unroll
  for (int n2 = 0; n2 < 16; ++n2) b[n2] = unpkc(tile_u[PHYS(16*t + n2, g)]);

  // ---- forward phase B -> S[t+16*k2] in registers
  fft16<-1>(b);

  // ---- spectral multiply from hot 16KB Wp slab (scaled W; unscale in K3)
  #pragma unroll
  for (int k2 = 0; k2 < 16; ++k2){
    cpx w = unpkc(wslab[(t + 16*k2)*16 + g]);
    b[k2] = cmul(b[k2], w);
  }

  // ---- inverse phase A (same stride-16 set), twiddle
  fft16<1>(b);
  #pragma unroll
  for (int k1 = 1; k1 < 16; ++k1){
    float2 tv = tw[(t * k1) & 255];
    cpx w; w.re = tv.x; w.im = tv.y;
    b[k1] = cmul(b[k1], w);
  }

  // ---- wave-local exchange 2
  __builtin_amdgcn_wave_barrier();
  #pragma unroll
  for (int k1 = 0; k1 < 16; ++k1) tile_u[PHYS(16*k1 + t, g)] = pkc(b[k1].re, b[k1].im);
  __builtin_amdgcn_wave_barrier();
  #pragma unroll
  for (int n2 = 0; n2 < 16; ++n2) b[n2] = unpkc(tile_u[PHYS(16*t + n2, g)]);

  // ---- inverse phase B; park packed for coalesced store
  fft16<1>(b);
  #pragma unroll
  for (int k2 = 0; k2 < 16; ++k2) tile_u[PHYS(t + 16*k2, g)] = pkc(b[k2].re, b[k2].im);
  __syncthreads();

  // ---- contiguous uint4 store back (in place)
  uint4* ob = (uint4*)base_u;
  #pragma unroll
  for (int it = 0; it < 4; ++it){
    int idx = it*256 + tid;
    int r = idx >> 2, q = idx & 3;
    ob[idx] = *(const uint4*)&tile_u[PHYS(r, 4*q)];
  }
}

// K3: irfft along b per (batch, a). DC/Nyquist imaginary parts dropped (c2r).
// Applies 1/(a*b) normalization AND the 1/256 W-prescale at the output store.
__global__ __launch_bounds__(512) void k3_irfft_b(const uint2* __restrict__ mid_p2,
                                                  float2* __restrict__ y2,
                                                  const float2* __restrict__ tw){
  __shared__ cpx tile[256*32];
  const int tid = threadIdx.x;
  const int blk = blockIdx.x;            // bb*256 + a
  const int bb = blk >> 8, a = blk & 255;
  const int g = tid >> 4, t = tid & 15;

  for (int it = 0; it < 9; ++it){
    int idx = it*512 + tid;
    if (idx < NF*32){
      int f = idx >> 5, gg = idx & 31;
      size_t o = ((((size_t)bb*NF + f)*4 + (gg >> 3))*256 + a)*8 + (gg & 7);
      uint2 pv = mid_p2[o];
      cpx A = unpkc(pv.x), B = unpkc(pv.y);
      cpx sd;
      if (f == 0 || f == 128){
        sd.re = A.re;                // Im(A), Im(B) dropped (c2r semantics)
        sd.im = B.re;
      } else {
        sd.re = A.re - B.im; sd.im = A.im + B.re;       // S[f] = A + iB
      }
      tile[PHY(f, gg)] = sd;
      if (f >= 1 && f <= 127){
        cpx se; se.re = A.re + B.im; se.im = B.re - A.im; // S[256-f]
        tile[PHY(256 - f, gg)] = se;
      }
    }
  }
  __syncthreads();

  fft256_col<+1>(tile, g, t, tw);

  const float SC = 5.9604644775390625e-08f;   // 1/65536 * 1/256 (W prescale)
  float2* dst = y2 + (size_t)blk * (256*32);
  #pragma unroll
  for (int it = 0; it < 16; ++it){
    int idx = it*512 + tid;
    int n = idx >> 5, gg = idx & 31;
    cpx v = tile[PHY(n, gg)];
    float2 o; o.x = v.re * SC; o.y = v.im * SC;
    dst[(size_t)n*32 + gg] = o;
  }
}

extern "C" void kernel_launch(void* const* d_in, const int* in_sizes, int n_in,
                              void* d_out, int out_size, void* d_ws, size_t ws_size,
                              hipStream_t stream){
  const float* x   = (const float*)d_in[0];
  const float* wre = (const float*)d_in[1];
  const float* wim = (const float*)d_in[2];

  float2* tw   = (float2*)d_ws;                        // 256 float2 = 2 KB
  uint*   wpck = (uint*)d_ws + 512;                    // Wp: 129*4*4096 uints ~8.45 MB
  uint*   midu = wpck + (size_t)NF*4*4096;             // packed fp16 mid, ~67.7 MB

  k0_twiddle  <<<1,      256, 0, stream>>>(tw);
  k0w_pack    <<<NF*4,   256, 0, stream>>>(wre, wim, wpck);
  k1_rfft_b   <<<NB*NA,  512, 0, stream>>>(x, (uint2*)midu, tw);
  k2_fft_a_mul<<<NF*32,  256, 0, stream>>>(midu, wpck, tw);
  k3_irfft_b  <<<NB*NA,  512, 0, stream>>>((const uint2*)midu, (float2*)d_out, tw);
}